// Round 5
// baseline (500.714 us; speedup 1.0000x reference)
//
#include <hip/hip_runtime.h>
#include <math.h>

// Chamfer distance, N=M=16384, D=3, fp32.
// R5: EXACT pruned nearest-neighbor search (brute force was issue-bound at
// 48.5 us with minimal 3.5 ops/pair -- R4; the win left is algorithmic).
// Points bucketed by x into 512 bins; queries processed in bucket-sorted
// order (we only need the SUM of per-point mins, so permutation is free).
// Each block expands candidate buckets left/right until every lane's
// current best squared distance <= squared distance to the nearest
// unprocessed bucket edge (conservative bound => exact result).
// Bucket sort is contention-free (per-block LDS histograms + two-level
// scan); R3 showed contended global atomics write through to HBM.
// min runs over (||b||^2 - 2 a.b); ||a||^2 re-added for pruning/epilogue.

constexpr int   NPTS  = 16384;
constexpr int   B     = 512;                  // x-bins
constexpr float X0    = -6.0f;                // bin range [-6, 6] (clamped)
constexpr float XW    = 12.0f / B;
constexpr float INV_W = B / 12.0f;
constexpr int   CB    = 128;                  // count/scatter blocks (64/set)
constexpr float INF_F = 3.402823466e+38f;

static __device__ __forceinline__ int bucket_of(float x) {
  int b = (int)floorf((x - X0) * INV_W);
  return min(max(b, 0), B - 1);
}

// ---- 1. per-block histograms: cnt_blk[blk][B] (blocks 0..63 = set A) ----
__global__ __launch_bounds__(256) void chamfer_bin(
    const float* __restrict__ p1, const float* __restrict__ p2,
    int* __restrict__ cnt_blk) {
  __shared__ int hist[B];
  const int tid = threadIdx.x;
  hist[tid] = 0;
  hist[tid + 256] = 0;
  __syncthreads();
  const int set = blockIdx.x >> 6;
  const int loc = (blockIdx.x & 63) * 256 + tid;
  const float* __restrict__ pts = set ? p2 : p1;
  atomicAdd(&hist[bucket_of(pts[loc * 3])], 1);
  __syncthreads();
  cnt_blk[blockIdx.x * B + tid] = hist[tid];
  cnt_blk[blockIdx.x * B + tid + 256] = hist[tid + 256];
}

// ---- 2. scan: bucket starts + per-(block,bin) scatter offsets ----
__global__ __launch_bounds__(B) void chamfer_scan(
    const int* __restrict__ cnt_blk, int* __restrict__ offs_blk,
    int* __restrict__ bstart, float* __restrict__ out) {
  __shared__ int sc[B];
  const int tid = threadIdx.x;
  for (int set = 0; set < 2; ++set) {
    const int kb = set * 64;
    int tot = 0;
    for (int k = 0; k < 64; ++k) tot += cnt_blk[(kb + k) * B + tid];
    sc[tid] = tot;
    __syncthreads();
    for (int off = 1; off < B; off <<= 1) {  // Hillis-Steele inclusive
      const int add = (tid >= off) ? sc[tid - off] : 0;
      __syncthreads();
      sc[tid] += add;
      __syncthreads();
    }
    const int base = sc[tid] - tot;  // exclusive
    bstart[set * (B + 1) + tid] = base;
    if (tid == 0) bstart[set * (B + 1) + B] = NPTS;
    int run = base;
    for (int k = 0; k < 64; ++k) {
      offs_blk[(kb + k) * B + tid] = run;
      run += cnt_blk[(kb + k) * B + tid];
    }
    __syncthreads();  // before sc reuse
  }
  if (tid == 0) out[0] = 0.0f;
}

// ---- 3. scatter to bucket-sorted float4 {x, y, z, ||p||^2} ----
__global__ __launch_bounds__(256) void chamfer_scatter(
    const float* __restrict__ p1, const float* __restrict__ p2,
    const int* __restrict__ offs_blk, float4* __restrict__ scat) {
  __shared__ int hist[B];
  const int tid = threadIdx.x;
  hist[tid] = 0;
  hist[tid + 256] = 0;
  __syncthreads();
  const int set = blockIdx.x >> 6;
  const int loc = (blockIdx.x & 63) * 256 + tid;
  const float* __restrict__ pts = set ? p2 : p1;
  const float x = pts[loc * 3 + 0];
  const float y = pts[loc * 3 + 1];
  const float z = pts[loc * 3 + 2];
  const int b = bucket_of(x);
  const int rank = atomicAdd(&hist[b], 1);           // LDS, low contention
  const int pos = offs_blk[blockIdx.x * B + b] + rank;
  scat[set * NPTS + pos] =
      make_float4(x, y, z, fmaf(x, x, fmaf(y, y, z * z)));
}

// ---- 4. search: 2 queries/lane, expand buckets until pruned ----
__global__ __launch_bounds__(64) void chamfer_search(
    const float4* __restrict__ scat, const int* __restrict__ bstart,
    float* __restrict__ out) {
  __shared__ float4 tile[64];
  const int tid  = threadIdx.x;
  const int bset = blockIdx.x >> 7;   // query set
  const int qblk = blockIdx.x & 127;
  const float4* __restrict__ qs = scat + bset * NPTS;
  const float4* __restrict__ ts = scat + (1 - bset) * NPTS;
  const int* __restrict__ tst = bstart + (1 - bset) * (B + 1);

  const float4 Q0 = qs[qblk * 128 + tid];
  const float4 Q1 = qs[qblk * 128 + tid + 64];
  const int cmin = __shfl(bucket_of(Q0.x), 0);   // sorted => lane0 is min
  const int cmax = __shfl(bucket_of(Q1.x), 63);  // lane63 is max

  float best0 = INF_F, best1 = INF_F;  // min of (||b||^2 - 2 a.b)

  auto process = [&](int t) {
    const int s = tst[t], e = tst[t + 1];
    for (int base = s; base < e; base += 64) {
      int n = e - base;
      if (n > 64) n = 64;
      __syncthreads();
      if (tid < n) {
        const float4 p = ts[base + tid];
        tile[tid] = make_float4(-2.0f * p.x, -2.0f * p.y, -2.0f * p.z, p.w);
      }
      __syncthreads();
      if (n == 64) {
#pragma unroll 8
        for (int k = 0; k < 64; ++k) {
          const float4 bb = tile[k];
          const float d0 = fmaf(Q0.x, bb.x, fmaf(Q0.y, bb.y, fmaf(Q0.z, bb.z, bb.w)));
          const float d1 = fmaf(Q1.x, bb.x, fmaf(Q1.y, bb.y, fmaf(Q1.z, bb.z, bb.w)));
          best0 = fminf(best0, d0);
          best1 = fminf(best1, d1);
        }
      } else {
        for (int k = 0; k < n; ++k) {
          const float4 bb = tile[k];
          const float d0 = fmaf(Q0.x, bb.x, fmaf(Q0.y, bb.y, fmaf(Q0.z, bb.z, bb.w)));
          const float d1 = fmaf(Q1.x, bb.x, fmaf(Q1.y, bb.y, fmaf(Q1.z, bb.z, bb.w)));
          best0 = fminf(best0, d0);
          best1 = fminf(best1, d1);
        }
      }
    }
  };

  for (int t = cmin; t <= cmax; ++t) process(t);
  int tl = cmin, tr = cmax;
  while (true) {
    const float b0 = best0 + Q0.w;  // actual min squared distance so far
    const float b1 = best1 + Q1.w;
    const float eL = X0 + tl * XW;        // processed-window left edge
    const float eR = X0 + (tr + 1) * XW;  // right edge
    const float dL0 = Q0.x - eL, dL1 = Q1.x - eL;
    const float dR0 = eR - Q0.x, dR1 = eR - Q1.x;
    const bool ndL = (tl > 0) && (b0 > dL0 * dL0 || b1 > dL1 * dL1);
    const bool ndR = (tr < B - 1) && (b0 > dR0 * dR0 || b1 > dR1 * dR1);
    const bool needL = __any(ndL);
    const bool needR = __any(ndR);
    if (!needL && !needR) break;
    if (needL) process(--tl);
    if (needR) process(++tr);
  }

  float s = sqrtf(fmaxf(best0 + Q0.w, 0.0f)) +
            sqrtf(fmaxf(best1 + Q1.w, 0.0f));
  for (int off = 32; off > 0; off >>= 1) s += __shfl_down(s, off, 64);
  if (tid == 0) atomicAdd(out, s);
}

extern "C" void kernel_launch(void* const* d_in, const int* in_sizes, int n_in,
                              void* d_out, int out_size, void* d_ws, size_t ws_size,
                              hipStream_t stream) {
  const float* p1 = (const float*)d_in[0];
  const float* p2 = (const float*)d_in[1];
  float* out = (float*)d_out;

  // ws layout (~1.03 MB): scat | cnt_blk | offs_blk | bstart
  float4* scat   = (float4*)d_ws;                 // 2*NPTS float4 (512 KB)
  int* cnt_blk   = (int*)(scat + 2 * NPTS);       // CB*B (256 KB)
  int* offs_blk  = cnt_blk + CB * B;              // CB*B (256 KB)
  int* bstart    = offs_blk + CB * B;             // 2*(B+1)

  chamfer_bin    <<<CB, 256, 0, stream>>>(p1, p2, cnt_blk);
  chamfer_scan   <<<1, B, 0, stream>>>(cnt_blk, offs_blk, bstart, out);
  chamfer_scatter<<<CB, 256, 0, stream>>>(p1, p2, offs_blk, scat);
  chamfer_search <<<256, 64, 0, stream>>>(scat, bstart, out);
}